// Round 6
// baseline (213.000 us; speedup 1.0000x reference)
//
#include <hip/hip_runtime.h>
#include <hip/hip_bf16.h>
#include <hip/hip_cooperative_groups.h>

namespace cg = cooperative_groups;

// GAT layer: out[b,i,j] = lrelu( (h@W@a1)[b,i] + (h@W@a2)[b,j] )
// B=4, N=4096, IN_F=256, OUT_F=64. Output: 4*4096*4096 fp32 = 256 MiB (write-bound).
// Single cooperative kernel: per block -> v (redundant, L2), own-row e1 (LDS) +
// e2 (global ws), grid.sync(), stream 16 output rows with e2 in registers.

#define B_DIM 4
#define N_DIM 4096
#define IN_F 256
#define OUT_F 64
#define SLOPE 0.2f

typedef float f32x4 __attribute__((ext_vector_type(4)));

__global__ __launch_bounds__(256, 4) void gat_fused(
        const float* __restrict__ h, const float* __restrict__ W,
        const float* __restrict__ a,
        float* __restrict__ e2g, float* __restrict__ out) {
    __shared__ float v1s[IN_F];
    __shared__ float v2s[IN_F];
    __shared__ float e1s[16];

    const int t    = threadIdx.x;
    const int lane = t & 63;
    const int wid  = t >> 6;
    const int bid  = blockIdx.x;

    // ---- phase A1: v = W @ a (wave-cooperative, coalesced; W is L2-resident) ----
    {
        const int rgrp = lane >> 4;   // row within quad: 0..3
        const int ch   = lane & 15;   // f32x4 chunk: 0..15
        const f32x4 a1c = reinterpret_cast<const f32x4*>(a)[ch];
        const f32x4 a2c = reinterpret_cast<const f32x4*>(a + OUT_F)[ch];
        #pragma unroll
        for (int it = 0; it < 16; ++it) {
            const int row = wid * 64 + it * 4 + rgrp;
            const f32x4 wv = *reinterpret_cast<const f32x4*>(W + row * OUT_F + ch * 4);
            float s1 = wv.x * a1c.x + wv.y * a1c.y + wv.z * a1c.z + wv.w * a1c.w;
            float s2 = wv.x * a2c.x + wv.y * a2c.y + wv.z * a2c.z + wv.w * a2c.w;
            #pragma unroll
            for (int m = 8; m >= 1; m >>= 1) {
                s1 += __shfl_xor(s1, m);
                s2 += __shfl_xor(s2, m);
            }
            if (ch == 0) {
                v1s[row] = s1;
                v2s[row] = s2;
            }
        }
    }
    __syncthreads();

    // ---- phase A2: this block's 16 rows: e1 -> LDS (local), e2 -> global ws ----
    {
        const f32x4 v1 = reinterpret_cast<const f32x4*>(v1s)[lane];
        const f32x4 v2 = reinterpret_cast<const f32x4*>(v2s)[lane];
        #pragma unroll
        for (int r = 0; r < 4; ++r) {
            const int lr  = wid * 4 + r;          // 0..15 local row
            const int row = bid * 16 + lr;
            const f32x4 hv = reinterpret_cast<const f32x4*>(h + (size_t)row * IN_F)[lane];
            float d1 = hv.x * v1.x + hv.y * v1.y + hv.z * v1.z + hv.w * v1.w;
            float d2 = hv.x * v2.x + hv.y * v2.y + hv.z * v2.z + hv.w * v2.w;
            #pragma unroll
            for (int m = 32; m >= 1; m >>= 1) {
                d1 += __shfl_xor(d1, m);
                d2 += __shfl_xor(d2, m);
            }
            if (lane == 0) {
                e1s[lr]   = d1;
                e2g[row]  = d2;
            }
        }
    }
    __threadfence();                 // make e2g visible device-wide
    cg::this_grid().sync();          // all e2 ready

    // ---- phase B: stream 16 output rows; e2 row cached in 16 regs ----
    const int rowBase = bid * 16;                  // 16 | 4096 -> single batch
    const int b       = rowBase >> 12;
    const f32x4* e2v  = reinterpret_cast<const f32x4*>(e2g + b * N_DIM);
    const f32x4 c0 = e2v[t];
    const f32x4 c1 = e2v[t + 256];
    const f32x4 c2 = e2v[t + 512];
    const f32x4 c3 = e2v[t + 768];

    float s[16];
    #pragma unroll
    for (int r = 0; r < 16; ++r) s[r] = e1s[r];    // LDS broadcast -> regs

    #pragma unroll
    for (int r = 0; r < 16; ++r) {
        f32x4* outv = reinterpret_cast<f32x4*>(out + (size_t)(rowBase + r) * N_DIM);
        f32x4 o0, o1, o2, o3;
        #define LRELU(dst, src) { \
            float ex = s[r] + (src).x; (dst).x = fmaxf(ex, SLOPE * ex); \
            float ey = s[r] + (src).y; (dst).y = fmaxf(ey, SLOPE * ey); \
            float ez = s[r] + (src).z; (dst).z = fmaxf(ez, SLOPE * ez); \
            float ew = s[r] + (src).w; (dst).w = fmaxf(ew, SLOPE * ew); }
        LRELU(o0, c0) LRELU(o1, c1) LRELU(o2, c2) LRELU(o3, c3)
        #undef LRELU
        outv[t]       = o0;
        outv[t + 256] = o1;
        outv[t + 512] = o2;
        outv[t + 768] = o3;
    }
}

extern "C" void kernel_launch(void* const* d_in, const int* in_sizes, int n_in,
                              void* d_out, int out_size, void* d_ws, size_t ws_size,
                              hipStream_t stream) {
    const float* h = (const float*)d_in[0];   // 4*4096*256
    const float* W = (const float*)d_in[1];   // 256*64
    const float* a = (const float*)d_in[2];   // 128
    float* e2g = (float*)d_ws;                // 16384 floats
    float* out = (float*)d_out;

    void* args[] = { (void*)&h, (void*)&W, (void*)&a, (void*)&e2g, (void*)&out };
    hipLaunchCooperativeKernel((void*)gat_fused, dim3(1024), dim3(256), args, 0, stream);
}

// Round 7
// 60.317 us; speedup vs baseline: 3.5314x; 3.5314x over previous
//
#include <hip/hip_runtime.h>
#include <hip/hip_bf16.h>

// GAT layer: out[b,i,j] = lrelu( (h@W@a1)[b,i] + (h@W@a2)[b,j] )
// B=4, N=4096, IN_F=256, OUT_F=64. Output: 4*4096*4096 fp32 = 256 MiB (write-bound).
// e1 = h@(W@a1), e2 = h@(W@a2) — Wh never materialized.
// Epilogue mimics the 7 TB/s fill-kernel regime: 256 blocks (4 waves/CU),
// grid-stride with stride ≡ 0 mod row, so e2 is loop-invariant per thread
// and the grid writes one ~1 MB window marching linearly through HBM.

#define B_DIM 4
#define N_DIM 4096
#define IN_F 256
#define OUT_F 64
#define SLOPE 0.2f

typedef float f32x4 __attribute__((ext_vector_type(4)));

// K1: fused v + dots. 1024 blocks x 256 threads (16 rows of h per block).
__global__ __launch_bounds__(256) void gat_dots(
        const float* __restrict__ h, const float* __restrict__ W,
        const float* __restrict__ a,
        float* __restrict__ e1, float* __restrict__ e2) {
    __shared__ float v1s[IN_F];
    __shared__ float v2s[IN_F];
    const int t    = threadIdx.x;
    const int lane = t & 63;
    const int wid  = t >> 6;

    // ---- phase 1: v = W @ a (coalesced, wave-cooperative) ----
    {
        const int rgrp = lane >> 4;
        const int ch   = lane & 15;
        const f32x4 a1c = reinterpret_cast<const f32x4*>(a)[ch];
        const f32x4 a2c = reinterpret_cast<const f32x4*>(a + OUT_F)[ch];
        #pragma unroll
        for (int it = 0; it < 16; ++it) {
            const int row = wid * 64 + it * 4 + rgrp;
            const f32x4 wv = *reinterpret_cast<const f32x4*>(W + row * OUT_F + ch * 4);
            float s1 = wv.x * a1c.x + wv.y * a1c.y + wv.z * a1c.z + wv.w * a1c.w;
            float s2 = wv.x * a2c.x + wv.y * a2c.y + wv.z * a2c.z + wv.w * a2c.w;
            #pragma unroll
            for (int m = 8; m >= 1; m >>= 1) {
                s1 += __shfl_xor(s1, m);
                s2 += __shfl_xor(s2, m);
            }
            if (ch == 0) { v1s[row] = s1; v2s[row] = s2; }
        }
    }
    __syncthreads();

    // ---- phase 2: wave-per-row dots (4 rows per wave) ----
    const f32x4 v1 = reinterpret_cast<const f32x4*>(v1s)[lane];
    const f32x4 v2 = reinterpret_cast<const f32x4*>(v2s)[lane];
    const int base = blockIdx.x * 16 + wid * 4;

    #pragma unroll
    for (int r = 0; r < 4; ++r) {
        const int row = base + r;
        const f32x4 hv = reinterpret_cast<const f32x4*>(h + (size_t)row * IN_F)[lane];
        float d1 = hv.x * v1.x + hv.y * v1.y + hv.z * v1.z + hv.w * v1.w;
        float d2 = hv.x * v2.x + hv.y * v2.y + hv.z * v2.z + hv.w * v2.w;
        #pragma unroll
        for (int m = 32; m >= 1; m >>= 1) {
            d1 += __shfl_xor(d1, m);
            d2 += __shfl_xor(d2, m);
        }
        if (lane == 0) { e1[row] = d1; e2[row] = d2; }
    }
}

// K2: epilogue, fill-kernel regime. 256 blocks x 256 threads = 65536 threads.
// Thread g: col4 = g & 1023 (CONSTANT over the loop), row0 = g >> 10 (0..63).
// Per batch: load e2 once, then 64 iterations row = row0 + 64*it, each a
// wave-uniform e1 scalar (prefetched) + 8 VALU + one dwordx4 store.
// Whole grid writes a 1 MB window that marches linearly -> max DRAM sequentiality.
__global__ __launch_bounds__(256) void gat_epilogue(
        const float* __restrict__ e1, const float* __restrict__ e2,
        float* __restrict__ out) {
    const int g    = blockIdx.x * 256 + threadIdx.x;   // 0..65535
    const int col4 = g & 1023;                          // f32x4 column
    const int row0 = g >> 10;                           // 0..63

    for (int b = 0; b < B_DIM; ++b) {
        const f32x4 c = reinterpret_cast<const f32x4*>(e2 + b * N_DIM)[col4];
        const float* e1b = e1 + b * N_DIM;
        f32x4* outb = reinterpret_cast<f32x4*>(out + (size_t)b * N_DIM * N_DIM);

        float s = e1b[row0];
        #pragma unroll 4
        for (int it = 0; it < 64; ++it) {
            const int row = row0 + it * 64;
            // prefetch next row's e1 (reads 64 floats past e1b end on last iter;
            // lands in e1/e2 workspace, never used)
            const float snext = e1b[row + 64];
            f32x4 o;
            float ex = s + c.x; o.x = fmaxf(ex, SLOPE * ex);
            float ey = s + c.y; o.y = fmaxf(ey, SLOPE * ey);
            float ez = s + c.z; o.z = fmaxf(ez, SLOPE * ez);
            float ew = s + c.w; o.w = fmaxf(ew, SLOPE * ew);
            outb[(size_t)row * (N_DIM / 4) + col4] = o;
            s = snext;
        }
    }
}

extern "C" void kernel_launch(void* const* d_in, const int* in_sizes, int n_in,
                              void* d_out, int out_size, void* d_ws, size_t ws_size,
                              hipStream_t stream) {
    const float* h = (const float*)d_in[0];   // 4*4096*256
    const float* W = (const float*)d_in[1];   // 256*64
    const float* a = (const float*)d_in[2];   // 128

    float* ws = (float*)d_ws;
    float* e1 = ws;                    // 16384 floats (indexed b*N + i)
    float* e2 = ws + 16384;            // 16384 floats (indexed b*N + j)

    gat_dots<<<1024, 256, 0, stream>>>(h, W, a, e1, e2);
    gat_epilogue<<<256, 256, 0, stream>>>(e1, e2, (float*)d_out);
}